// Round 2
// baseline (722.482 us; speedup 1.0000x reference)
//
#include <hip/hip_runtime.h>

#define DD 128

// ---------- zero counts ----------
__global__ void zero_k(int* __restrict__ p, int n) {
  int i = blockIdx.x * 256 + threadIdx.x;
  if (i < n) p[i] = 0;
}

// ---------- histogram of row indices ----------
__global__ void hist_k(const int* __restrict__ rowi, int* __restrict__ cnt, int E) {
  int e = blockIdx.x * 256 + threadIdx.x;
  if (e < E) atomicAdd(&cnt[rowi[e]], 1);
}

// ---------- exclusive scan (1 block, 1024 threads) ----------
__global__ void scan_k(const int* __restrict__ cnt, int* __restrict__ rowptr,
                       int* __restrict__ cursor, int n) {
  __shared__ int part[1024];
  int tid = threadIdx.x;
  int M = n + 1;
  int chunk = (M + 1023) >> 10;
  int beg = tid * chunk;
  int end = beg + chunk < M ? beg + chunk : M;
  int s = 0;
  for (int i = beg; i < end; ++i) s += (i < n) ? cnt[i] : 0;
  part[tid] = s;
  __syncthreads();
  for (int off = 1; off < 1024; off <<= 1) {
    int v = (tid >= off) ? part[tid - off] : 0;
    __syncthreads();
    part[tid] += v;
    __syncthreads();
  }
  int run = part[tid] - s;  // exclusive prefix of this thread's range
  for (int i = beg; i < end; ++i) {
    rowptr[i] = run;
    cursor[i] = run;
    run += (i < n) ? cnt[i] : 0;
  }
}

// ---------- scatter edges into CSR order ----------
__global__ void scatter_k(const int* __restrict__ rowi, const int* __restrict__ coli,
                          const float* __restrict__ vals, int* __restrict__ cursor,
                          int* __restrict__ colS, float* __restrict__ valS, int E) {
  int e = blockIdx.x * 256 + threadIdx.x;
  if (e < E) {
    int r = rowi[e];
    int p = atomicAdd(&cursor[r], 1);
    colS[p] = coli[e];
    valS[p] = vals[e];
  }
}

// ---------- W2 = IM @ w_lin^T  (IM = (1-beta) + beta*weight) ----------
__global__ void w2_k(const float* __restrict__ weight, const float* __restrict__ w_lin,
                     float* __restrict__ W2) {
  const float BETA = 0.40546510810816438f;  // log(1.5)
  int idx = blockIdx.x * 256 + threadIdx.x; // 0..16383 exact
  int i = idx >> 7, j = idx & 127;
  const float* wi = weight + i * DD;
  const float* lj = w_lin + j * DD;
  float s = 0.f;
#pragma unroll 8
  for (int k = 0; k < DD; ++k) s = fmaf(fmaf(BETA, wi[k], 1.0f - BETA), lj[k], s);
  W2[idx] = s;  // W2[i][j]
}

// ---------- Wf (f32, [k=256][n=128]): rows 0..127 = 0.9*W2, rows 128..255 = 0.1*w_h0^T@W2 ----------
__global__ void wt_k(const float* __restrict__ W2, const float* __restrict__ w_h0,
                     const float* __restrict__ b_h0, const float* __restrict__ b_lin,
                     float* __restrict__ Wf, float* __restrict__ cvec) {
  int idx = blockIdx.x * 256 + threadIdx.x;
  if (idx < 16384) {
    Wf[idx] = 0.9f * W2[idx];                       // Wf[k][n] = 0.9*W2[k][n]
  } else if (idx < 32768) {
    int t = idx - 16384;
    int p = t >> 7, n = t & 127;
    float s = 0.f;
#pragma unroll 8
    for (int k = 0; k < DD; ++k) s = fmaf(w_h0[k * DD + p], W2[k * DD + n], s);
    Wf[(128 + p) * DD + n] = 0.1f * s;              // B[p][n] = sum_k w_h0[k][p]*W2[k][n]
  } else if (idx < 32896) {
    int n = idx - 32768;
    float s = 0.f;
    for (int k = 0; k < DD; ++k) s = fmaf(b_h0[k], W2[k * DD + n], s);
    cvec[n] = fmaf(0.1f, s, b_lin[n]);
  }
}

// ---------- per-row gather SpMM: S = ego + A_in@ego  (one wave per row) ----------
__global__ void gather_k(const float* __restrict__ ego, const int* __restrict__ colS,
                         const float* __restrict__ valS, const int* __restrict__ rowptr,
                         float* S, int n) {
  int w = (blockIdx.x * 256 + threadIdx.x) >> 6;
  if (w >= n) return;
  int lane = threadIdx.x & 63;
  const float2* eg2 = (const float2*)ego;
  float2 acc = eg2[(size_t)w * 64 + lane];
  int e = rowptr[w], end = rowptr[w + 1];
  for (; e + 1 < end; e += 2) {
    int c0 = colS[e], c1 = colS[e + 1];
    float v0 = valS[e], v1 = valS[e + 1];
    float2 g0 = eg2[(size_t)c0 * 64 + lane];
    float2 g1 = eg2[(size_t)c1 * 64 + lane];
    acc.x = fmaf(v0, g0.x, acc.x);
    acc.y = fmaf(v0, g0.y, acc.y);
    acc.x = fmaf(v1, g1.x, acc.x);
    acc.y = fmaf(v1, g1.y, acc.y);
  }
  if (e < end) {
    int c0 = colS[e];
    float v0 = valS[e];
    float2 g0 = eg2[(size_t)c0 * 64 + lane];
    acc.x = fmaf(v0, g0.x, acc.x);
    acc.y = fmaf(v0, g0.y, acc.y);
  }
  ((float2*)S)[(size_t)w * 64 + lane] = acc;
}

// ---------- fused f32 GEMM + bias + LeakyReLU + LayerNorm ----------
// out[r][:] = LN( leaky( [S[r], h0[r]] @ Wf + c ) ),  Wf is [256][128] row-major.
// Block = 256 threads = 4 waves; each wave owns 16 rows. Lane owns cols {lane, lane+64}.
__global__ __launch_bounds__(256) void dense_f32(
    const float* S, const float* __restrict__ h0, const float* __restrict__ Wf,
    const float* __restrict__ cvec, const float* __restrict__ gamma,
    const float* __restrict__ betaln, float* out, int n) {
  __shared__ float lds[4][4096];  // 64 KiB: per-wave 16 rows x 256 cols staging
  int wave = threadIdx.x >> 6;
  int lane = threadIdx.x & 63;
  float* xs = &lds[wave][0];
  int row0 = blockIdx.x * 64 + wave * 16;

  // ---- stage X = [S | h0] rows into LDS (each wave stages only its own rows) ----
  {
    int c4 = lane * 4;
#pragma unroll
    for (int t = 0; t < 16; ++t) {
      int r = row0 + t;
      if (r >= n) r = n - 1;
      float4 v;
      if (c4 < 128) v = *(const float4*)(S + (size_t)r * DD + c4);
      else          v = *(const float4*)(h0 + (size_t)r * DD + (c4 - 128));
      *(float4*)(xs + t * 256 + c4) = v;
    }
  }
  __syncthreads();

  // ---- k-loop: 256 k in steps of 4 ----
  float acc0[16], acc1[16];
#pragma unroll
  for (int r = 0; r < 16; ++r) { acc0[r] = 0.f; acc1[r] = 0.f; }

  for (int kb = 0; kb < 64; ++kb) {
    int k = kb * 4;
    float wA0 = Wf[(k + 0) * DD + lane];
    float wA1 = Wf[(k + 1) * DD + lane];
    float wA2 = Wf[(k + 2) * DD + lane];
    float wA3 = Wf[(k + 3) * DD + lane];
    float wB0 = Wf[(k + 0) * DD + 64 + lane];
    float wB1 = Wf[(k + 1) * DD + 64 + lane];
    float wB2 = Wf[(k + 2) * DD + 64 + lane];
    float wB3 = Wf[(k + 3) * DD + 64 + lane];
#pragma unroll
    for (int r = 0; r < 16; ++r) {
      float4 xv = *(const float4*)(xs + r * 256 + k);
      acc0[r] = fmaf(xv.x, wA0, acc0[r]);
      acc0[r] = fmaf(xv.y, wA1, acc0[r]);
      acc0[r] = fmaf(xv.z, wA2, acc0[r]);
      acc0[r] = fmaf(xv.w, wA3, acc0[r]);
      acc1[r] = fmaf(xv.x, wB0, acc1[r]);
      acc1[r] = fmaf(xv.y, wB1, acc1[r]);
      acc1[r] = fmaf(xv.z, wB2, acc1[r]);
      acc1[r] = fmaf(xv.w, wB3, acc1[r]);
    }
  }

  // ---- epilogue: bias + leaky, stash row-major (stride 132) in LDS ----
  float cb0 = cvec[lane], cb1 = cvec[64 + lane];
#pragma unroll
  for (int r = 0; r < 16; ++r) {
    float t0 = acc0[r] + cb0;
    t0 = (t0 > 0.f) ? t0 : 0.01f * t0;
    float t1 = acc1[r] + cb1;
    t1 = (t1 > 0.f) ? t1 : 0.01f * t1;
    xs[r * 132 + lane] = t0;
    xs[r * 132 + 64 + lane] = t1;
  }
  // same wave reads its own region; in-order DS ops make this safe without a barrier

  // ---- LN: lane -> (row = lane>>2, 32-col chunk p = lane&3) ----
  int r = lane >> 2, p = lane & 3;
  const float* base = xs + r * 132 + p * 32;
  float4 va[8];
  float s = 0.f, q = 0.f;
#pragma unroll
  for (int j = 0; j < 8; ++j) {
    float4 t = *(const float4*)(base + j * 4);
    va[j] = t;
    s += t.x + t.y + t.z + t.w;
    q = fmaf(t.x, t.x, q);
    q = fmaf(t.y, t.y, q);
    q = fmaf(t.z, t.z, q);
    q = fmaf(t.w, t.w, q);
  }
  s += __shfl_xor(s, 1, 64);
  s += __shfl_xor(s, 2, 64);
  q += __shfl_xor(q, 1, 64);
  q += __shfl_xor(q, 2, 64);
  float mean = s * (1.f / 128.f);
  float var = fmaf(q, 1.f / 128.f, -mean * mean);
  float rstd = rsqrtf(var + 1e-5f);

  int orow = row0 + r;
  if (orow < n) {
    float* op = out + (size_t)orow * DD + p * 32;
    const float* gp = gamma + p * 32;
    const float* bp = betaln + p * 32;
#pragma unroll
    for (int j = 0; j < 8; ++j) {
      float4 g = *(const float4*)(gp + j * 4);
      float4 b = *(const float4*)(bp + j * 4);
      float4 o;
      o.x = fmaf((va[j].x - mean) * rstd, g.x, b.x);
      o.y = fmaf((va[j].y - mean) * rstd, g.y, b.y);
      o.z = fmaf((va[j].z - mean) * rstd, g.z, b.z);
      o.w = fmaf((va[j].w - mean) * rstd, g.w, b.w);
      *(float4*)(op + j * 4) = o;
    }
  }
}

extern "C" void kernel_launch(void* const* d_in, const int* in_sizes, int n_in,
                              void* d_out, int out_size, void* d_ws, size_t ws_size,
                              hipStream_t stream) {
  const float* ego    = (const float*)d_in[0];
  const float* h0     = (const float*)d_in[1];
  const float* vals   = (const float*)d_in[2];
  const int*   rowi   = (const int*)d_in[3];
  const int*   coli   = (const int*)d_in[4];
  const float* weight = (const float*)d_in[5];
  const float* w_h0   = (const float*)d_in[6];
  const float* b_h0   = (const float*)d_in[7];
  const float* w_lin  = (const float*)d_in[8];
  const float* b_lin  = (const float*)d_in[9];
  const float* gamma  = (const float*)d_in[10];
  const float* betaln = (const float*)d_in[11];

  const int N = in_sizes[0] / DD;
  const int E = in_sizes[2];

  char* p = (char*)d_ws;
  auto carve = [&](size_t bytes) {
    char* q = p;
    p += (bytes + 255) & ~(size_t)255;
    return q;
  };
  int*   cnt    = (int*)carve((size_t)N * 4);
  int*   rowptr = (int*)carve((size_t)(N + 1) * 4);
  int*   cursor = (int*)carve((size_t)(N + 1) * 4);
  int*   colS   = (int*)carve((size_t)E * 4);
  float* valS   = (float*)carve((size_t)E * 4);
  float* W2     = (float*)carve(16384 * 4);
  float* Wf     = (float*)carve(32768 * 4);
  float* cvec   = (float*)carve(128 * 4);
  // S buffer: prefer workspace (no aliasing); fall back to d_out reuse.
  size_t used = (size_t)(p - (char*)d_ws);
  float* Sbuf;
  if (used + (size_t)N * DD * 4 <= ws_size) {
    Sbuf = (float*)carve((size_t)N * DD * 4);
  } else {
    Sbuf = (float*)d_out;
  }
  (void)n_in; (void)out_size;

  float* outf = (float*)d_out;

  zero_k<<<(N + 255) / 256, 256, 0, stream>>>(cnt, N);
  hist_k<<<(E + 255) / 256, 256, 0, stream>>>(rowi, cnt, E);
  w2_k<<<64, 256, 0, stream>>>(weight, w_lin, W2);
  scan_k<<<1, 1024, 0, stream>>>(cnt, rowptr, cursor, N);
  scatter_k<<<(E + 255) / 256, 256, 0, stream>>>(rowi, coli, vals, cursor, colS, valS, E);
  wt_k<<<129, 256, 0, stream>>>(W2, w_h0, b_h0, b_lin, Wf, cvec);
  gather_k<<<(N + 3) / 4, 256, 0, stream>>>(ego, colS, valS, rowptr, Sbuf, N);
  dense_f32<<<(N + 63) / 64, 256, 0, stream>>>(Sbuf, h0, Wf, cvec, gamma, betaln, outf, N);
}

// Round 3
// 476.269 us; speedup vs baseline: 1.5170x; 1.5170x over previous
//
#include <hip/hip_runtime.h>

#define DD 128

// ---------- histogram of row indices ----------
__global__ void hist_k(const int* __restrict__ rowi, int* __restrict__ cnt, int E) {
  int e = blockIdx.x * 256 + threadIdx.x;
  if (e < E) atomicAdd(&cnt[rowi[e]], 1);
}

// ---------- scan stage 1: per-block (1024 elems) sums ----------
__global__ __launch_bounds__(256) void scan1_k(const int* __restrict__ cnt,
                                               int* __restrict__ bsum, int n) {
  __shared__ int red[256];
  int base = blockIdx.x * 1024 + threadIdx.x * 4;
  int s = 0;
  if (base + 3 < n) {
    int4 v = *(const int4*)(cnt + base);
    s = v.x + v.y + v.z + v.w;
  } else {
#pragma unroll
    for (int j = 0; j < 4; ++j) if (base + j < n) s += cnt[base + j];
  }
  red[threadIdx.x] = s;
  __syncthreads();
#pragma unroll
  for (int off = 128; off > 0; off >>= 1) {
    if (threadIdx.x < off) red[threadIdx.x] += red[threadIdx.x + off];
    __syncthreads();
  }
  if (threadIdx.x == 0) bsum[blockIdx.x] = red[0];
}

// ---------- scan stage 2: exclusive scan of block sums (nb <= 256) ----------
__global__ __launch_bounds__(256) void scan2_k(int* __restrict__ bsum, int nb) {
  __shared__ int part[256];
  int t = threadIdx.x;
  int v = (t < nb) ? bsum[t] : 0;
  part[t] = v;
  __syncthreads();
#pragma unroll
  for (int off = 1; off < 256; off <<= 1) {
    int u = (t >= off) ? part[t - off] : 0;
    __syncthreads();
    part[t] += u;
    __syncthreads();
  }
  if (t < nb) bsum[t] = part[t] - v;  // exclusive prefix
}

// ---------- scan stage 3: local scan + global offset -> rowptr, cursor ----------
__global__ __launch_bounds__(256) void scan3_k(const int* __restrict__ cnt,
                                               const int* __restrict__ bsum,
                                               int* __restrict__ rowptr,
                                               int* __restrict__ cursor, int n, int E) {
  __shared__ int tsum[256];
  int base = blockIdx.x * 1024 + threadIdx.x * 4;
  int v0 = 0, v1 = 0, v2 = 0, v3 = 0;
  if (base + 3 < n) {
    int4 v = *(const int4*)(cnt + base);
    v0 = v.x; v1 = v.y; v2 = v.z; v3 = v.w;
  } else {
    if (base + 0 < n) v0 = cnt[base + 0];
    if (base + 1 < n) v1 = cnt[base + 1];
    if (base + 2 < n) v2 = cnt[base + 2];
    if (base + 3 < n) v3 = cnt[base + 3];
  }
  int s = v0 + v1 + v2 + v3;
  tsum[threadIdx.x] = s;
  __syncthreads();
#pragma unroll
  for (int off = 1; off < 256; off <<= 1) {
    int u = (threadIdx.x >= off) ? tsum[threadIdx.x - off] : 0;
    __syncthreads();
    tsum[threadIdx.x] += u;
    __syncthreads();
  }
  int run = bsum[blockIdx.x] + tsum[threadIdx.x] - s;  // exclusive for this thread
  int p1 = run + v0, p2 = p1 + v1, p3 = p2 + v2;
  if (base + 3 < n) {
    *(int4*)(rowptr + base) = (int4){run, p1, p2, p3};
    *(int4*)(cursor + base) = (int4){run, p1, p2, p3};
  } else {
    if (base + 0 < n) { rowptr[base + 0] = run; cursor[base + 0] = run; }
    if (base + 1 < n) { rowptr[base + 1] = p1;  cursor[base + 1] = p1; }
    if (base + 2 < n) { rowptr[base + 2] = p2;  cursor[base + 2] = p2; }
    if (base + 3 < n) { rowptr[base + 3] = p3;  cursor[base + 3] = p3; }
  }
  if (blockIdx.x == 0 && threadIdx.x == 0) rowptr[n] = E;
}

// ---------- scatter edges into CSR order ----------
__global__ void scatter_k(const int* __restrict__ rowi, const int* __restrict__ coli,
                          const float* __restrict__ vals, int* __restrict__ cursor,
                          int* __restrict__ colS, float* __restrict__ valS, int E) {
  int e = blockIdx.x * 256 + threadIdx.x;
  if (e < E) {
    int r = rowi[e];
    int p = atomicAdd(&cursor[r], 1);
    colS[p] = coli[e];
    valS[p] = vals[e];
  }
}

// ---------- W2 = IM @ w_lin^T  (IM = (1-beta) + beta*weight) ----------
__global__ void w2_k(const float* __restrict__ weight, const float* __restrict__ w_lin,
                     float* __restrict__ W2) {
  const float BETA = 0.40546510810816438f;  // log(1.5)
  int idx = blockIdx.x * 256 + threadIdx.x; // 0..16383 exact
  int i = idx >> 7, j = idx & 127;
  const float* wi = weight + i * DD;
  const float* lj = w_lin + j * DD;
  float s = 0.f;
#pragma unroll 8
  for (int k = 0; k < DD; ++k) s = fmaf(fmaf(BETA, wi[k], 1.0f - BETA), lj[k], s);
  W2[idx] = s;  // W2[i][j]
}

// ---------- Wf (f32, [k=256][n=128]): rows 0..127 = 0.9*W2, rows 128..255 = 0.1*w_h0^T@W2 ----------
__global__ void wt_k(const float* __restrict__ W2, const float* __restrict__ w_h0,
                     const float* __restrict__ b_h0, const float* __restrict__ b_lin,
                     float* __restrict__ Wf, float* __restrict__ cvec) {
  int idx = blockIdx.x * 256 + threadIdx.x;
  if (idx < 16384) {
    Wf[idx] = 0.9f * W2[idx];                       // Wf[k][n] = 0.9*W2[k][n]
  } else if (idx < 32768) {
    int t = idx - 16384;
    int p = t >> 7, n = t & 127;
    float s = 0.f;
#pragma unroll 8
    for (int k = 0; k < DD; ++k) s = fmaf(w_h0[k * DD + p], W2[k * DD + n], s);
    Wf[(128 + p) * DD + n] = 0.1f * s;              // B[p][n] = sum_k w_h0[k][p]*W2[k][n]
  } else if (idx < 32896) {
    int n = idx - 32768;
    float s = 0.f;
    for (int k = 0; k < DD; ++k) s = fmaf(b_h0[k], W2[k * DD + n], s);
    cvec[n] = fmaf(0.1f, s, b_lin[n]);
  }
}

// ---------- per-row gather SpMM: S = ego + A_in@ego  (one wave per row) ----------
__global__ void gather_k(const float* __restrict__ ego, const int* __restrict__ colS,
                         const float* __restrict__ valS, const int* __restrict__ rowptr,
                         float* S, int n) {
  int w = (blockIdx.x * 256 + threadIdx.x) >> 6;
  if (w >= n) return;
  int lane = threadIdx.x & 63;
  const float2* eg2 = (const float2*)ego;
  float2 acc = eg2[(size_t)w * 64 + lane];
  float2 acc2 = {0.f, 0.f};
  int e = rowptr[w], end = rowptr[w + 1];
  for (; e + 3 < end; e += 4) {
    int c0 = colS[e], c1 = colS[e + 1], c2 = colS[e + 2], c3 = colS[e + 3];
    float v0 = valS[e], v1 = valS[e + 1], v2 = valS[e + 2], v3 = valS[e + 3];
    float2 g0 = eg2[(size_t)c0 * 64 + lane];
    float2 g1 = eg2[(size_t)c1 * 64 + lane];
    float2 g2 = eg2[(size_t)c2 * 64 + lane];
    float2 g3 = eg2[(size_t)c3 * 64 + lane];
    acc.x  = fmaf(v0, g0.x, acc.x);  acc.y  = fmaf(v0, g0.y, acc.y);
    acc2.x = fmaf(v1, g1.x, acc2.x); acc2.y = fmaf(v1, g1.y, acc2.y);
    acc.x  = fmaf(v2, g2.x, acc.x);  acc.y  = fmaf(v2, g2.y, acc.y);
    acc2.x = fmaf(v3, g3.x, acc2.x); acc2.y = fmaf(v3, g3.y, acc2.y);
  }
  for (; e < end; ++e) {
    int c0 = colS[e];
    float v0 = valS[e];
    float2 g0 = eg2[(size_t)c0 * 64 + lane];
    acc.x = fmaf(v0, g0.x, acc.x);
    acc.y = fmaf(v0, g0.y, acc.y);
  }
  acc.x += acc2.x;
  acc.y += acc2.y;
  ((float2*)S)[(size_t)w * 64 + lane] = acc;
}

// ---------- fused f32 GEMM + bias + LeakyReLU + LayerNorm ----------
// out[r][:] = LN( leaky( [S[r], h0[r]] @ Wf + c ) ),  Wf is [256][128] row-major.
__global__ __launch_bounds__(256) void dense_f32(
    const float* S, const float* __restrict__ h0, const float* __restrict__ Wf,
    const float* __restrict__ cvec, const float* __restrict__ gamma,
    const float* __restrict__ betaln, float* out, int n) {
  __shared__ float lds[4][4096];  // 64 KiB: per-wave 16 rows x 256 cols staging
  int wave = threadIdx.x >> 6;
  int lane = threadIdx.x & 63;
  float* xs = &lds[wave][0];
  int row0 = blockIdx.x * 64 + wave * 16;

  // ---- stage X = [S | h0] rows into LDS (each wave stages only its own rows) ----
  {
    int c4 = lane * 4;
#pragma unroll
    for (int t = 0; t < 16; ++t) {
      int r = row0 + t;
      if (r >= n) r = n - 1;
      float4 v;
      if (c4 < 128) v = *(const float4*)(S + (size_t)r * DD + c4);
      else          v = *(const float4*)(h0 + (size_t)r * DD + (c4 - 128));
      *(float4*)(xs + t * 256 + c4) = v;
    }
  }
  __syncthreads();

  // ---- k-loop: 256 k in steps of 4 ----
  float acc0[16], acc1[16];
#pragma unroll
  for (int r = 0; r < 16; ++r) { acc0[r] = 0.f; acc1[r] = 0.f; }

  for (int kb = 0; kb < 64; ++kb) {
    int k = kb * 4;
    float wA0 = Wf[(k + 0) * DD + lane];
    float wA1 = Wf[(k + 1) * DD + lane];
    float wA2 = Wf[(k + 2) * DD + lane];
    float wA3 = Wf[(k + 3) * DD + lane];
    float wB0 = Wf[(k + 0) * DD + 64 + lane];
    float wB1 = Wf[(k + 1) * DD + 64 + lane];
    float wB2 = Wf[(k + 2) * DD + 64 + lane];
    float wB3 = Wf[(k + 3) * DD + 64 + lane];
#pragma unroll
    for (int r = 0; r < 16; ++r) {
      float4 xv = *(const float4*)(xs + r * 256 + k);
      acc0[r] = fmaf(xv.x, wA0, acc0[r]);
      acc0[r] = fmaf(xv.y, wA1, acc0[r]);
      acc0[r] = fmaf(xv.z, wA2, acc0[r]);
      acc0[r] = fmaf(xv.w, wA3, acc0[r]);
      acc1[r] = fmaf(xv.x, wB0, acc1[r]);
      acc1[r] = fmaf(xv.y, wB1, acc1[r]);
      acc1[r] = fmaf(xv.z, wB2, acc1[r]);
      acc1[r] = fmaf(xv.w, wB3, acc1[r]);
    }
  }

  // ---- epilogue: bias + leaky, stash row-major (stride 132) in LDS ----
  float cb0 = cvec[lane], cb1 = cvec[64 + lane];
#pragma unroll
  for (int r = 0; r < 16; ++r) {
    float t0 = acc0[r] + cb0;
    t0 = (t0 > 0.f) ? t0 : 0.01f * t0;
    float t1 = acc1[r] + cb1;
    t1 = (t1 > 0.f) ? t1 : 0.01f * t1;
    xs[r * 132 + lane] = t0;
    xs[r * 132 + 64 + lane] = t1;
  }
  // same wave reads its own region; in-order DS ops make this safe without a barrier

  // ---- LN: lane -> (row = lane>>2, 32-col chunk p = lane&3) ----
  int r = lane >> 2, p = lane & 3;
  const float* base = xs + r * 132 + p * 32;
  float4 va[8];
  float s = 0.f, q = 0.f;
#pragma unroll
  for (int j = 0; j < 8; ++j) {
    float4 t = *(const float4*)(base + j * 4);
    va[j] = t;
    s += t.x + t.y + t.z + t.w;
    q = fmaf(t.x, t.x, q);
    q = fmaf(t.y, t.y, q);
    q = fmaf(t.z, t.z, q);
    q = fmaf(t.w, t.w, q);
  }
  s += __shfl_xor(s, 1, 64);
  s += __shfl_xor(s, 2, 64);
  q += __shfl_xor(q, 1, 64);
  q += __shfl_xor(q, 2, 64);
  float mean = s * (1.f / 128.f);
  float var = fmaf(q, 1.f / 128.f, -mean * mean);
  float rstd = rsqrtf(var + 1e-5f);

  int orow = row0 + r;
  if (orow < n) {
    float* op = out + (size_t)orow * DD + p * 32;
    const float* gp = gamma + p * 32;
    const float* bp = betaln + p * 32;
#pragma unroll
    for (int j = 0; j < 8; ++j) {
      float4 g = *(const float4*)(gp + j * 4);
      float4 b = *(const float4*)(bp + j * 4);
      float4 o;
      o.x = fmaf((va[j].x - mean) * rstd, g.x, b.x);
      o.y = fmaf((va[j].y - mean) * rstd, g.y, b.y);
      o.z = fmaf((va[j].z - mean) * rstd, g.z, b.z);
      o.w = fmaf((va[j].w - mean) * rstd, g.w, b.w);
      *(float4*)(op + j * 4) = o;
    }
  }
}

extern "C" void kernel_launch(void* const* d_in, const int* in_sizes, int n_in,
                              void* d_out, int out_size, void* d_ws, size_t ws_size,
                              hipStream_t stream) {
  const float* ego    = (const float*)d_in[0];
  const float* h0     = (const float*)d_in[1];
  const float* vals   = (const float*)d_in[2];
  const int*   rowi   = (const int*)d_in[3];
  const int*   coli   = (const int*)d_in[4];
  const float* weight = (const float*)d_in[5];
  const float* w_h0   = (const float*)d_in[6];
  const float* b_h0   = (const float*)d_in[7];
  const float* w_lin  = (const float*)d_in[8];
  const float* b_lin  = (const float*)d_in[9];
  const float* gamma  = (const float*)d_in[10];
  const float* betaln = (const float*)d_in[11];

  const int N = in_sizes[0] / DD;
  const int E = in_sizes[2];
  const int NB = (N + 1023) / 1024;  // scan blocks (98 for N=100000, <=256 required)

  char* p = (char*)d_ws;
  auto carve = [&](size_t bytes) {
    char* q = p;
    p += (bytes + 255) & ~(size_t)255;
    return q;
  };
  int*   cnt    = (int*)carve((size_t)N * 4);
  int*   rowptr = (int*)carve((size_t)(N + 1) * 4);
  int*   cursor = (int*)carve((size_t)(N + 1) * 4);
  int*   bsum   = (int*)carve((size_t)256 * 4);
  int*   colS   = (int*)carve((size_t)E * 4);
  float* valS   = (float*)carve((size_t)E * 4);
  float* W2     = (float*)carve(16384 * 4);
  float* Wf     = (float*)carve(32768 * 4);
  float* cvec   = (float*)carve(128 * 4);
  // S buffer: prefer workspace (no aliasing); fall back to d_out reuse.
  size_t used = (size_t)(p - (char*)d_ws);
  float* Sbuf;
  if (used + (size_t)N * DD * 4 <= ws_size) {
    Sbuf = (float*)carve((size_t)N * DD * 4);
  } else {
    Sbuf = (float*)d_out;
  }
  (void)n_in; (void)out_size;

  float* outf = (float*)d_out;

  hipMemsetAsync(cnt, 0, (size_t)N * 4, stream);
  hist_k<<<(E + 255) / 256, 256, 0, stream>>>(rowi, cnt, E);
  w2_k<<<64, 256, 0, stream>>>(weight, w_lin, W2);
  scan1_k<<<NB, 256, 0, stream>>>(cnt, bsum, N);
  scan2_k<<<1, 256, 0, stream>>>(bsum, NB);
  scan3_k<<<NB, 256, 0, stream>>>(cnt, bsum, rowptr, cursor, N, E);
  scatter_k<<<(E + 255) / 256, 256, 0, stream>>>(rowi, coli, vals, cursor, colS, valS, E);
  wt_k<<<129, 256, 0, stream>>>(W2, w_h0, b_h0, b_lin, Wf, cvec);
  gather_k<<<(N + 3) / 4, 256, 0, stream>>>(ego, colS, valS, rowptr, Sbuf, N);
  dense_ln_guard:
  dense_f32<<<(N + 63) / 64, 256, 0, stream>>>(Sbuf, h0, Wf, cvec, gamma, betaln, outf, N);
}

// Round 4
// 452.134 us; speedup vs baseline: 1.5979x; 1.0534x over previous
//
#include <hip/hip_runtime.h>

#define DD 128

// ---------- histogram of row indices ----------
__global__ void hist_k(const int* __restrict__ rowi, int* __restrict__ cnt, int E) {
  int e = blockIdx.x * 256 + threadIdx.x;
  if (e < E) atomicAdd(&cnt[rowi[e]], 1);
}

// ---------- scan stage 1: per-block (1024 elems) sums ----------
__global__ __launch_bounds__(256) void scan1_k(const int* __restrict__ cnt,
                                               int* __restrict__ bsum, int n) {
  __shared__ int red[256];
  int base = blockIdx.x * 1024 + threadIdx.x * 4;
  int s = 0;
  if (base + 3 < n) {
    int4 v = *(const int4*)(cnt + base);
    s = v.x + v.y + v.z + v.w;
  } else {
#pragma unroll
    for (int j = 0; j < 4; ++j) if (base + j < n) s += cnt[base + j];
  }
  red[threadIdx.x] = s;
  __syncthreads();
#pragma unroll
  for (int off = 128; off > 0; off >>= 1) {
    if (threadIdx.x < off) red[threadIdx.x] += red[threadIdx.x + off];
    __syncthreads();
  }
  if (threadIdx.x == 0) bsum[blockIdx.x] = red[0];
}

// ---------- scan stage 2: exclusive scan of block sums (nb <= 256) ----------
__global__ __launch_bounds__(256) void scan2_k(int* __restrict__ bsum, int nb) {
  __shared__ int part[256];
  int t = threadIdx.x;
  int v = (t < nb) ? bsum[t] : 0;
  part[t] = v;
  __syncthreads();
#pragma unroll
  for (int off = 1; off < 256; off <<= 1) {
    int u = (t >= off) ? part[t - off] : 0;
    __syncthreads();
    part[t] += u;
    __syncthreads();
  }
  if (t < nb) bsum[t] = part[t] - v;  // exclusive prefix
}

// ---------- scan stage 3: local scan + global offset -> rowptr, cursor ----------
__global__ __launch_bounds__(256) void scan3_k(const int* __restrict__ cnt,
                                               const int* __restrict__ bsum,
                                               int* __restrict__ rowptr,
                                               int* __restrict__ cursor, int n, int E) {
  __shared__ int tsum[256];
  int base = blockIdx.x * 1024 + threadIdx.x * 4;
  int v0 = 0, v1 = 0, v2 = 0, v3 = 0;
  if (base + 3 < n) {
    int4 v = *(const int4*)(cnt + base);
    v0 = v.x; v1 = v.y; v2 = v.z; v3 = v.w;
  } else {
    if (base + 0 < n) v0 = cnt[base + 0];
    if (base + 1 < n) v1 = cnt[base + 1];
    if (base + 2 < n) v2 = cnt[base + 2];
    if (base + 3 < n) v3 = cnt[base + 3];
  }
  int s = v0 + v1 + v2 + v3;
  tsum[threadIdx.x] = s;
  __syncthreads();
#pragma unroll
  for (int off = 1; off < 256; off <<= 1) {
    int u = (threadIdx.x >= off) ? tsum[threadIdx.x - off] : 0;
    __syncthreads();
    tsum[threadIdx.x] += u;
    __syncthreads();
  }
  int run = bsum[blockIdx.x] + tsum[threadIdx.x] - s;  // exclusive for this thread
  int p1 = run + v0, p2 = p1 + v1, p3 = p2 + v2;
  if (base + 3 < n) {
    *(int4*)(rowptr + base) = (int4){run, p1, p2, p3};
    *(int4*)(cursor + base) = (int4){run, p1, p2, p3};
  } else {
    if (base + 0 < n) { rowptr[base + 0] = run; cursor[base + 0] = run; }
    if (base + 1 < n) { rowptr[base + 1] = p1;  cursor[base + 1] = p1; }
    if (base + 2 < n) { rowptr[base + 2] = p2;  cursor[base + 2] = p2; }
    if (base + 3 < n) { rowptr[base + 3] = p3;  cursor[base + 3] = p3; }
  }
  if (blockIdx.x == 0 && threadIdx.x == 0) rowptr[n] = E;
}

// ---------- scatter edges into CSR order ----------
__global__ void scatter_k(const int* __restrict__ rowi, const int* __restrict__ coli,
                          const float* __restrict__ vals, int* __restrict__ cursor,
                          int* __restrict__ colS, float* __restrict__ valS, int E) {
  int e = blockIdx.x * 256 + threadIdx.x;
  if (e < E) {
    int r = rowi[e];
    int p = atomicAdd(&cursor[r], 1);
    colS[p] = coli[e];
    valS[p] = vals[e];
  }
}

// ---------- W2 = IM @ w_lin^T  (IM = (1-beta) + beta*weight) ----------
__global__ void w2_k(const float* __restrict__ weight, const float* __restrict__ w_lin,
                     float* __restrict__ W2) {
  const float BETA = 0.40546510810816438f;  // log(1.5)
  int idx = blockIdx.x * 256 + threadIdx.x; // 0..16383 exact
  int i = idx >> 7, j = idx & 127;
  const float* wi = weight + i * DD;
  const float* lj = w_lin + j * DD;
  float s = 0.f;
#pragma unroll 8
  for (int k = 0; k < DD; ++k) s = fmaf(fmaf(BETA, wi[k], 1.0f - BETA), lj[k], s);
  W2[idx] = s;  // W2[i][j]
}

// ---------- Wf (f32, [k=256][n=128]): rows 0..127 = 0.9*W2, rows 128..255 = 0.1*w_h0^T@W2 ----------
__global__ void wt_k(const float* __restrict__ W2, const float* __restrict__ w_h0,
                     const float* __restrict__ b_h0, const float* __restrict__ b_lin,
                     float* __restrict__ Wf, float* __restrict__ cvec) {
  int idx = blockIdx.x * 256 + threadIdx.x;
  if (idx < 16384) {
    Wf[idx] = 0.9f * W2[idx];                       // Wf[k][n] = 0.9*W2[k][n]
  } else if (idx < 32768) {
    int t = idx - 16384;
    int p = t >> 7, n = t & 127;
    float s = 0.f;
#pragma unroll 8
    for (int k = 0; k < DD; ++k) s = fmaf(w_h0[k * DD + p], W2[k * DD + n], s);
    Wf[(128 + p) * DD + n] = 0.1f * s;              // B[p][n] = sum_k w_h0[k][p]*W2[k][n]
  } else if (idx < 32896) {
    int n = idx - 32768;
    float s = 0.f;
    for (int k = 0; k < DD; ++k) s = fmaf(b_h0[k], W2[k * DD + n], s);
    cvec[n] = fmaf(0.1f, s, b_lin[n]);
  }
}

// ---------- fused: per-row gather SpMM -> f32 GEMM -> bias+LeakyReLU+LayerNorm ----------
// Block = 256 threads = 4 waves; each wave owns 8 rows (block = 32 rows).
// Phase 1: wave gathers S[r] = ego[r] + sum v*ego[col] straight into its LDS region,
//          and stages h0[r] alongside -> X = [S | h0] (256 wide).
// Phase 2: lane owns output cols {lane, 64+lane}; k-loop over 256 with Wf broadcast.
// No __syncthreads needed: each wave only touches its own LDS region (in-order DS).
__global__ __launch_bounds__(256) void fused_k(
    const float* __restrict__ ego, const int* __restrict__ colS,
    const float* __restrict__ valS, const int* __restrict__ rowptr,
    const float* __restrict__ h0, const float* __restrict__ Wf,
    const float* __restrict__ cvec, const float* __restrict__ gamma,
    const float* __restrict__ betaln, float* __restrict__ out, int n) {
  __shared__ float lds[4][2048];  // 32 KiB total: per-wave 8 rows x 256 cols
  int wave = threadIdx.x >> 6;
  int lane = threadIdx.x & 63;
  float* xs = &lds[wave][0];
  int row0 = blockIdx.x * 32 + wave * 8;
  const float2* eg2 = (const float2*)ego;
  const float2* h2 = (const float2*)h0;

  // ---- phase 1: gather 8 rows into LDS ----
#pragma unroll
  for (int t = 0; t < 8; ++t) {
    int r = row0 + t;
    if (r >= n) r = n - 1;
    float2 acc = eg2[(size_t)r * 64 + lane];
    float2 acc2 = {0.f, 0.f};
    int e = rowptr[r], end = rowptr[r + 1];
    for (; e + 3 < end; e += 4) {
      int c0 = colS[e], c1 = colS[e + 1], c2 = colS[e + 2], c3 = colS[e + 3];
      float v0 = valS[e], v1 = valS[e + 1], v2 = valS[e + 2], v3 = valS[e + 3];
      float2 g0 = eg2[(size_t)c0 * 64 + lane];
      float2 g1 = eg2[(size_t)c1 * 64 + lane];
      float2 g2 = eg2[(size_t)c2 * 64 + lane];
      float2 g3 = eg2[(size_t)c3 * 64 + lane];
      acc.x  = fmaf(v0, g0.x, acc.x);  acc.y  = fmaf(v0, g0.y, acc.y);
      acc2.x = fmaf(v1, g1.x, acc2.x); acc2.y = fmaf(v1, g1.y, acc2.y);
      acc.x  = fmaf(v2, g2.x, acc.x);  acc.y  = fmaf(v2, g2.y, acc.y);
      acc2.x = fmaf(v3, g3.x, acc2.x); acc2.y = fmaf(v3, g3.y, acc2.y);
    }
    for (; e < end; ++e) {
      int c0 = colS[e];
      float v0 = valS[e];
      float2 g0 = eg2[(size_t)c0 * 64 + lane];
      acc.x = fmaf(v0, g0.x, acc.x);
      acc.y = fmaf(v0, g0.y, acc.y);
    }
    acc.x += acc2.x;
    acc.y += acc2.y;
    *(float2*)(xs + t * 256 + 2 * lane) = acc;                       // S part
    *(float2*)(xs + t * 256 + 128 + 2 * lane) = h2[(size_t)r * 64 + lane];  // h0 part
  }

  // ---- phase 2: GEMM, 8 rows x 2 cols per lane, k = 0..255 step 4 ----
  float acc0[8], acc1[8];
#pragma unroll
  for (int r = 0; r < 8; ++r) { acc0[r] = 0.f; acc1[r] = 0.f; }

  for (int kb = 0; kb < 64; ++kb) {
    int k = kb * 4;
    float wA0 = Wf[(k + 0) * DD + lane];
    float wA1 = Wf[(k + 1) * DD + lane];
    float wA2 = Wf[(k + 2) * DD + lane];
    float wA3 = Wf[(k + 3) * DD + lane];
    float wB0 = Wf[(k + 0) * DD + 64 + lane];
    float wB1 = Wf[(k + 1) * DD + 64 + lane];
    float wB2 = Wf[(k + 2) * DD + 64 + lane];
    float wB3 = Wf[(k + 3) * DD + 64 + lane];
#pragma unroll
    for (int r = 0; r < 8; ++r) {
      float4 xv = *(const float4*)(xs + r * 256 + k);  // broadcast, conflict-free
      acc0[r] = fmaf(xv.x, wA0, acc0[r]);
      acc0[r] = fmaf(xv.y, wA1, acc0[r]);
      acc0[r] = fmaf(xv.z, wA2, acc0[r]);
      acc0[r] = fmaf(xv.w, wA3, acc0[r]);
      acc1[r] = fmaf(xv.x, wB0, acc1[r]);
      acc1[r] = fmaf(xv.y, wB1, acc1[r]);
      acc1[r] = fmaf(xv.z, wB2, acc1[r]);
      acc1[r] = fmaf(xv.w, wB3, acc1[r]);
    }
  }

  // ---- epilogue: bias + leaky, stash rows (stride 132) in own LDS region ----
  float cb0 = cvec[lane], cb1 = cvec[64 + lane];
#pragma unroll
  for (int r = 0; r < 8; ++r) {
    float t0 = acc0[r] + cb0;
    t0 = (t0 > 0.f) ? t0 : 0.01f * t0;
    float t1 = acc1[r] + cb1;
    t1 = (t1 > 0.f) ? t1 : 0.01f * t1;
    xs[r * 132 + lane] = t0;
    xs[r * 132 + 64 + lane] = t1;
  }

  // ---- LN: lane -> (row = lane>>3, 16-col chunk p = lane&7) ----
  int r = lane >> 3, p = lane & 7;
  const float* base = xs + r * 132 + p * 16;  // 16B-aligned: 132*4*r and 64*p both %16==0
  float4 va[4];
  float s = 0.f, q = 0.f;
#pragma unroll
  for (int j = 0; j < 4; ++j) {
    float4 t = *(const float4*)(base + j * 4);
    va[j] = t;
    s += t.x + t.y + t.z + t.w;
    q = fmaf(t.x, t.x, q);
    q = fmaf(t.y, t.y, q);
    q = fmaf(t.z, t.z, q);
    q = fmaf(t.w, t.w, q);
  }
  s += __shfl_xor(s, 1, 64);
  s += __shfl_xor(s, 2, 64);
  s += __shfl_xor(s, 4, 64);
  q += __shfl_xor(q, 1, 64);
  q += __shfl_xor(q, 2, 64);
  q += __shfl_xor(q, 4, 64);
  float mean = s * (1.f / 128.f);
  float var = fmaf(q, 1.f / 128.f, -mean * mean);
  float rstd = rsqrtf(var + 1e-5f);

  int orow = row0 + r;
  if (orow < n) {
    float* op = out + (size_t)orow * DD + p * 16;
    const float* gp = gamma + p * 16;
    const float* bp = betaln + p * 16;
#pragma unroll
    for (int j = 0; j < 4; ++j) {
      float4 g = *(const float4*)(gp + j * 4);
      float4 b = *(const float4*)(bp + j * 4);
      float4 o;
      o.x = fmaf((va[j].x - mean) * rstd, g.x, b.x);
      o.y = fmaf((va[j].y - mean) * rstd, g.y, b.y);
      o.z = fmaf((va[j].z - mean) * rstd, g.z, b.z);
      o.w = fmaf((va[j].w - mean) * rstd, g.w, b.w);
      *(float4*)(op + j * 4) = o;
    }
  }
}

extern "C" void kernel_launch(void* const* d_in, const int* in_sizes, int n_in,
                              void* d_out, int out_size, void* d_ws, size_t ws_size,
                              hipStream_t stream) {
  const float* ego    = (const float*)d_in[0];
  const float* h0     = (const float*)d_in[1];
  const float* vals   = (const float*)d_in[2];
  const int*   rowi   = (const int*)d_in[3];
  const int*   coli   = (const int*)d_in[4];
  const float* weight = (const float*)d_in[5];
  const float* w_h0   = (const float*)d_in[6];
  const float* b_h0   = (const float*)d_in[7];
  const float* w_lin  = (const float*)d_in[8];
  const float* b_lin  = (const float*)d_in[9];
  const float* gamma  = (const float*)d_in[10];
  const float* betaln = (const float*)d_in[11];

  const int N = in_sizes[0] / DD;
  const int E = in_sizes[2];
  const int NB = (N + 1023) / 1024;  // scan blocks (98 for N=100000, <=256 required)

  char* p = (char*)d_ws;
  auto carve = [&](size_t bytes) {
    char* q = p;
    p += (bytes + 255) & ~(size_t)255;
    return q;
  };
  int*   cnt    = (int*)carve((size_t)N * 4);
  int*   rowptr = (int*)carve((size_t)(N + 1) * 4);
  int*   cursor = (int*)carve((size_t)(N + 1) * 4);
  int*   bsum   = (int*)carve((size_t)256 * 4);
  int*   colS   = (int*)carve((size_t)E * 4);
  float* valS   = (float*)carve((size_t)E * 4);
  float* W2     = (float*)carve(16384 * 4);
  float* Wf     = (float*)carve(32768 * 4);
  float* cvec   = (float*)carve(128 * 4);
  (void)n_in; (void)out_size; (void)ws_size;

  float* outf = (float*)d_out;

  hipMemsetAsync(cnt, 0, (size_t)N * 4, stream);
  hist_k<<<(E + 255) / 256, 256, 0, stream>>>(rowi, cnt, E);
  w2_k<<<64, 256, 0, stream>>>(weight, w_lin, W2);
  scan1_k<<<NB, 256, 0, stream>>>(cnt, bsum, N);
  scan2_k<<<1, 256, 0, stream>>>(bsum, NB);
  scan3_k<<<NB, 256, 0, stream>>>(cnt, bsum, rowptr, cursor, N, E);
  scatter_k<<<(E + 255) / 256, 256, 0, stream>>>(rowi, coli, vals, cursor, colS, valS, E);
  wt_k<<<129, 256, 0, stream>>>(W2, w_h0, b_h0, b_lin, Wf, cvec);
  fused_k<<<(N + 31) / 32, 256, 0, stream>>>(ego, colS, valS, rowptr, h0, Wf, cvec,
                                             gamma, betaln, outf, N);
}

// Round 5
// 427.565 us; speedup vs baseline: 1.6898x; 1.0575x over previous
//
#include <hip/hip_runtime.h>

#define DD 128

// ---------- histogram of row indices ----------
__global__ void hist_k(const int* __restrict__ rowi, int* __restrict__ cnt, int E) {
  int e = blockIdx.x * 256 + threadIdx.x;
  if (e < E) atomicAdd(&cnt[rowi[e]], 1);
}

// ---------- scan stage 1: per-block (1024 elems) sums ----------
__global__ __launch_bounds__(256) void scan1_k(const int* __restrict__ cnt,
                                               int* __restrict__ bsum, int n) {
  __shared__ int red[256];
  int base = blockIdx.x * 1024 + threadIdx.x * 4;
  int s = 0;
  if (base + 3 < n) {
    int4 v = *(const int4*)(cnt + base);
    s = v.x + v.y + v.z + v.w;
  } else {
#pragma unroll
    for (int j = 0; j < 4; ++j) if (base + j < n) s += cnt[base + j];
  }
  red[threadIdx.x] = s;
  __syncthreads();
#pragma unroll
  for (int off = 128; off > 0; off >>= 1) {
    if (threadIdx.x < off) red[threadIdx.x] += red[threadIdx.x + off];
    __syncthreads();
  }
  if (threadIdx.x == 0) bsum[blockIdx.x] = red[0];
}

// ---------- scan stage 2: exclusive scan of block sums (nb <= 256) ----------
__global__ __launch_bounds__(256) void scan2_k(int* __restrict__ bsum, int nb) {
  __shared__ int part[256];
  int t = threadIdx.x;
  int v = (t < nb) ? bsum[t] : 0;
  part[t] = v;
  __syncthreads();
#pragma unroll
  for (int off = 1; off < 256; off <<= 1) {
    int u = (t >= off) ? part[t - off] : 0;
    __syncthreads();
    part[t] += u;
    __syncthreads();
  }
  if (t < nb) bsum[t] = part[t] - v;  // exclusive prefix
}

// ---------- scan stage 3: local scan + global offset -> rowptr, cursor ----------
__global__ __launch_bounds__(256) void scan3_k(const int* __restrict__ cnt,
                                               const int* __restrict__ bsum,
                                               int* __restrict__ rowptr,
                                               int* __restrict__ cursor, int n, int E) {
  __shared__ int tsum[256];
  int base = blockIdx.x * 1024 + threadIdx.x * 4;
  int v0 = 0, v1 = 0, v2 = 0, v3 = 0;
  if (base + 3 < n) {
    int4 v = *(const int4*)(cnt + base);
    v0 = v.x; v1 = v.y; v2 = v.z; v3 = v.w;
  } else {
    if (base + 0 < n) v0 = cnt[base + 0];
    if (base + 1 < n) v1 = cnt[base + 1];
    if (base + 2 < n) v2 = cnt[base + 2];
    if (base + 3 < n) v3 = cnt[base + 3];
  }
  int s = v0 + v1 + v2 + v3;
  tsum[threadIdx.x] = s;
  __syncthreads();
#pragma unroll
  for (int off = 1; off < 256; off <<= 1) {
    int u = (threadIdx.x >= off) ? tsum[threadIdx.x - off] : 0;
    __syncthreads();
    tsum[threadIdx.x] += u;
    __syncthreads();
  }
  int run = bsum[blockIdx.x] + tsum[threadIdx.x] - s;  // exclusive for this thread
  int p1 = run + v0, p2 = p1 + v1, p3 = p2 + v2;
  if (base + 3 < n) {
    *(int4*)(rowptr + base) = (int4){run, p1, p2, p3};
    *(int4*)(cursor + base) = (int4){run, p1, p2, p3};
  } else {
    if (base + 0 < n) { rowptr[base + 0] = run; cursor[base + 0] = run; }
    if (base + 1 < n) { rowptr[base + 1] = p1;  cursor[base + 1] = p1; }
    if (base + 2 < n) { rowptr[base + 2] = p2;  cursor[base + 2] = p2; }
    if (base + 3 < n) { rowptr[base + 3] = p3;  cursor[base + 3] = p3; }
  }
  if (blockIdx.x == 0 && threadIdx.x == 0) rowptr[n] = E;
}

// ---------- scatter edges into CSR order (packed int2: col, val-bits) ----------
__global__ void scatter_k(const int* __restrict__ rowi, const int* __restrict__ coli,
                          const float* __restrict__ vals, int* __restrict__ cursor,
                          int2* __restrict__ edgeS, int E) {
  int e = blockIdx.x * 256 + threadIdx.x;
  if (e < E) {
    int r = rowi[e];
    int p = atomicAdd(&cursor[r], 1);
    edgeS[p] = make_int2(coli[e], __float_as_int(vals[e]));
  }
}

// ---------- W2 = IM @ w_lin^T  (IM = (1-beta) + beta*weight) ----------
__global__ void w2_k(const float* __restrict__ weight, const float* __restrict__ w_lin,
                     float* __restrict__ W2) {
  const float BETA = 0.40546510810816438f;  // log(1.5)
  int idx = blockIdx.x * 256 + threadIdx.x; // 0..16383 exact
  int i = idx >> 7, j = idx & 127;
  const float* wi = weight + i * DD;
  const float* lj = w_lin + j * DD;
  float s = 0.f;
#pragma unroll 8
  for (int k = 0; k < DD; ++k) s = fmaf(fmaf(BETA, wi[k], 1.0f - BETA), lj[k], s);
  W2[idx] = s;  // W2[i][j]
}

// ---------- Wf (f32, [k=256][n=128]): rows 0..127 = 0.9*W2, rows 128..255 = 0.1*w_h0^T@W2 ----------
__global__ void wt_k(const float* __restrict__ W2, const float* __restrict__ w_h0,
                     const float* __restrict__ b_h0, const float* __restrict__ b_lin,
                     float* __restrict__ Wf, float* __restrict__ cvec) {
  int idx = blockIdx.x * 256 + threadIdx.x;
  if (idx < 16384) {
    Wf[idx] = 0.9f * W2[idx];                       // Wf[k][n] = 0.9*W2[k][n]
  } else if (idx < 32768) {
    int t = idx - 16384;
    int p = t >> 7, n = t & 127;
    float s = 0.f;
#pragma unroll 8
    for (int k = 0; k < DD; ++k) s = fmaf(w_h0[k * DD + p], W2[k * DD + n], s);
    Wf[(128 + p) * DD + n] = 0.1f * s;              // B[p][n] = sum_k w_h0[k][p]*W2[k][n]
  } else if (idx < 32896) {
    int n = idx - 32768;
    float s = 0.f;
    for (int k = 0; k < DD; ++k) s = fmaf(b_h0[k], W2[k * DD + n], s);
    cvec[n] = fmaf(0.1f, s, b_lin[n]);
  }
}

// ---------- fused: gather SpMM -> f32 GEMM -> bias+LeakyReLU+LayerNorm ----------
// Block = 256 threads = 4 waves; each wave owns 8 rows.
// Gather: lanes 0-31 process even edges, lanes 32-63 odd edges; each lane loads a
// float4 (one gather instr = 2 full rows). Halves folded with shfl_xor(32).
// No __syncthreads needed: each wave only touches its own LDS region.
__global__ __launch_bounds__(256) void fused_k(
    const float* __restrict__ ego, const int2* __restrict__ edgeS,
    const int* __restrict__ rowptr, const float* __restrict__ h0,
    const float* __restrict__ Wf, const float* __restrict__ cvec,
    const float* __restrict__ gamma, const float* __restrict__ betaln,
    float* __restrict__ out, int n, int E) {
  __shared__ float lds[4][2048];  // 32 KiB total: per-wave 8 rows x 256 cols
  int wave = threadIdx.x >> 6;
  int lane = threadIdx.x & 63;
  int half = lane >> 5;   // 0 = even edges / S-writer, 1 = odd edges / h0-writer
  int q = lane & 31;      // float4 slot within a row
  float* xs = &lds[wave][0];
  int row0 = blockIdx.x * 32 + wave * 8;
  const float4* eg4 = (const float4*)ego;
  const float4* h4 = (const float4*)h0;

  // ---- phase 1: gather 8 rows into LDS ----
#pragma unroll
  for (int t = 0; t < 8; ++t) {
    int r = row0 + t;
    if (r >= n) r = n - 1;
    float4 acc;
    if (half == 0) acc = eg4[(size_t)r * 32 + q];
    else           acc = (float4){0.f, 0.f, 0.f, 0.f};
    float4 hrow = h4[(size_t)r * 32 + q];  // both halves load same lines (free)
    int beg = rowptr[r], end = rowptr[r + 1];
    int e = beg;
    for (; e + 8 <= end; e += 8) {
      int2 m0 = edgeS[e + 0 + half];
      int2 m1 = edgeS[e + 2 + half];
      int2 m2 = edgeS[e + 4 + half];
      int2 m3 = edgeS[e + 6 + half];
      float4 g0 = eg4[(size_t)m0.x * 32 + q];
      float4 g1 = eg4[(size_t)m1.x * 32 + q];
      float4 g2 = eg4[(size_t)m2.x * 32 + q];
      float4 g3 = eg4[(size_t)m3.x * 32 + q];
      float v0 = __int_as_float(m0.y), v1 = __int_as_float(m1.y);
      float v2 = __int_as_float(m2.y), v3 = __int_as_float(m3.y);
      acc.x = fmaf(v0, g0.x, acc.x); acc.y = fmaf(v0, g0.y, acc.y);
      acc.z = fmaf(v0, g0.z, acc.z); acc.w = fmaf(v0, g0.w, acc.w);
      acc.x = fmaf(v1, g1.x, acc.x); acc.y = fmaf(v1, g1.y, acc.y);
      acc.z = fmaf(v1, g1.z, acc.z); acc.w = fmaf(v1, g1.w, acc.w);
      acc.x = fmaf(v2, g2.x, acc.x); acc.y = fmaf(v2, g2.y, acc.y);
      acc.z = fmaf(v2, g2.z, acc.z); acc.w = fmaf(v2, g2.w, acc.w);
      acc.x = fmaf(v3, g3.x, acc.x); acc.y = fmaf(v3, g3.y, acc.y);
      acc.z = fmaf(v3, g3.z, acc.z); acc.w = fmaf(v3, g3.w, acc.w);
    }
    for (; e < end; e += 2) {
      int idx = e + half;
      bool ok = idx < end;
      int ci = ok ? idx : (E > idx ? idx : E - 1);   // safe index
      if (ci >= E) ci = E - 1;
      int2 m = edgeS[ci];
      float v = ok ? __int_as_float(m.y) : 0.f;
      float4 g = eg4[(size_t)m.x * 32 + q];
      acc.x = fmaf(v, g.x, acc.x); acc.y = fmaf(v, g.y, acc.y);
      acc.z = fmaf(v, g.z, acc.z); acc.w = fmaf(v, g.w, acc.w);
    }
    // fold halves (each lane pair q / q+32 holds partials of cols 4q..4q+3)
    acc.x += __shfl_xor(acc.x, 32, 64);
    acc.y += __shfl_xor(acc.y, 32, 64);
    acc.z += __shfl_xor(acc.z, 32, 64);
    acc.w += __shfl_xor(acc.w, 32, 64);
    if (half == 0) *(float4*)(xs + t * 256 + 4 * q) = acc;        // S part
    else           *(float4*)(xs + t * 256 + 128 + 4 * q) = hrow; // h0 part
  }

  // ---- phase 2: GEMM, 8 rows x 2 cols per lane, k = 0..255 step 4 ----
  float acc0[8], acc1[8];
#pragma unroll
  for (int r = 0; r < 8; ++r) { acc0[r] = 0.f; acc1[r] = 0.f; }

  for (int kb = 0; kb < 64; ++kb) {
    int k = kb * 4;
    float wA0 = Wf[(k + 0) * DD + lane];
    float wA1 = Wf[(k + 1) * DD + lane];
    float wA2 = Wf[(k + 2) * DD + lane];
    float wA3 = Wf[(k + 3) * DD + lane];
    float wB0 = Wf[(k + 0) * DD + 64 + lane];
    float wB1 = Wf[(k + 1) * DD + 64 + lane];
    float wB2 = Wf[(k + 2) * DD + 64 + lane];
    float wB3 = Wf[(k + 3) * DD + 64 + lane];
#pragma unroll
    for (int r = 0; r < 8; ++r) {
      float4 xv = *(const float4*)(xs + r * 256 + k);  // broadcast, conflict-free
      acc0[r] = fmaf(xv.x, wA0, acc0[r]);
      acc0[r] = fmaf(xv.y, wA1, acc0[r]);
      acc0[r] = fmaf(xv.z, wA2, acc0[r]);
      acc0[r] = fmaf(xv.w, wA3, acc0[r]);
      acc1[r] = fmaf(xv.x, wB0, acc1[r]);
      acc1[r] = fmaf(xv.y, wB1, acc1[r]);
      acc1[r] = fmaf(xv.z, wB2, acc1[r]);
      acc1[r] = fmaf(xv.w, wB3, acc1[r]);
    }
  }

  // ---- epilogue: bias + leaky, stash rows (stride 132) in own LDS region ----
  float cb0 = cvec[lane], cb1 = cvec[64 + lane];
#pragma unroll
  for (int r = 0; r < 8; ++r) {
    float t0 = acc0[r] + cb0;
    t0 = (t0 > 0.f) ? t0 : 0.01f * t0;
    float t1 = acc1[r] + cb1;
    t1 = (t1 > 0.f) ? t1 : 0.01f * t1;
    xs[r * 132 + lane] = t0;
    xs[r * 132 + 64 + lane] = t1;
  }

  // ---- LN: lane -> (row = lane>>3, 16-col chunk p = lane&7) ----
  int r = lane >> 3, p = lane & 7;
  const float* base = xs + r * 132 + p * 16;  // 16B-aligned
  float4 va[4];
  float s = 0.f, qq = 0.f;
#pragma unroll
  for (int j = 0; j < 4; ++j) {
    float4 t = *(const float4*)(base + j * 4);
    va[j] = t;
    s += t.x + t.y + t.z + t.w;
    qq = fmaf(t.x, t.x, qq);
    qq = fmaf(t.y, t.y, qq);
    qq = fmaf(t.z, t.z, qq);
    qq = fmaf(t.w, t.w, qq);
  }
  s += __shfl_xor(s, 1, 64);
  s += __shfl_xor(s, 2, 64);
  s += __shfl_xor(s, 4, 64);
  qq += __shfl_xor(qq, 1, 64);
  qq += __shfl_xor(qq, 2, 64);
  qq += __shfl_xor(qq, 4, 64);
  float mean = s * (1.f / 128.f);
  float var = fmaf(qq, 1.f / 128.f, -mean * mean);
  float rstd = rsqrtf(var + 1e-5f);

  int orow = row0 + r;
  if (orow < n) {
    float* op = out + (size_t)orow * DD + p * 16;
    const float* gp = gamma + p * 16;
    const float* bp = betaln + p * 16;
#pragma unroll
    for (int j = 0; j < 4; ++j) {
      float4 g = *(const float4*)(gp + j * 4);
      float4 b = *(const float4*)(bp + j * 4);
      float4 o;
      o.x = fmaf((va[j].x - mean) * rstd, g.x, b.x);
      o.y = fmaf((va[j].y - mean) * rstd, g.y, b.y);
      o.z = fmaf((va[j].z - mean) * rstd, g.z, b.z);
      o.w = fmaf((va[j].w - mean) * rstd, g.w, b.w);
      *(float4*)(op + j * 4) = o;
    }
  }
}

extern "C" void kernel_launch(void* const* d_in, const int* in_sizes, int n_in,
                              void* d_out, int out_size, void* d_ws, size_t ws_size,
                              hipStream_t stream) {
  const float* ego    = (const float*)d_in[0];
  const float* h0     = (const float*)d_in[1];
  const float* vals   = (const float*)d_in[2];
  const int*   rowi   = (const int*)d_in[3];
  const int*   coli   = (const int*)d_in[4];
  const float* weight = (const float*)d_in[5];
  const float* w_h0   = (const float*)d_in[6];
  const float* b_h0   = (const float*)d_in[7];
  const float* w_lin  = (const float*)d_in[8];
  const float* b_lin  = (const float*)d_in[9];
  const float* gamma  = (const float*)d_in[10];
  const float* betaln = (const float*)d_in[11];

  const int N = in_sizes[0] / DD;
  const int E = in_sizes[2];
  const int NB = (N + 1023) / 1024;  // scan blocks (98 for N=100000, <=256 required)

  char* p = (char*)d_ws;
  auto carve = [&](size_t bytes) {
    char* q = p;
    p += (bytes + 255) & ~(size_t)255;
    return q;
  };
  int*   cnt    = (int*)carve((size_t)N * 4);
  int*   rowptr = (int*)carve((size_t)(N + 1) * 4);
  int*   cursor = (int*)carve((size_t)(N + 1) * 4);
  int*   bsum   = (int*)carve((size_t)256 * 4);
  int2*  edgeS  = (int2*)carve((size_t)E * 8);
  float* W2     = (float*)carve(16384 * 4);
  float* Wf     = (float*)carve(32768 * 4);
  float* cvec   = (float*)carve(128 * 4);
  (void)n_in; (void)out_size; (void)ws_size;

  float* outf = (float*)d_out;

  hipMemsetAsync(cnt, 0, (size_t)N * 4, stream);
  hist_k<<<(E + 255) / 256, 256, 0, stream>>>(rowi, cnt, E);
  w2_k<<<64, 256, 0, stream>>>(weight, w_lin, W2);
  scan1_k<<<NB, 256, 0, stream>>>(cnt, bsum, N);
  scan2_k<<<1, 256, 0, stream>>>(bsum, NB);
  scan3_k<<<NB, 256, 0, stream>>>(cnt, bsum, rowptr, cursor, N, E);
  scatter_k<<<(E + 255) / 256, 256, 0, stream>>>(rowi, coli, vals, cursor, edgeS, E);
  wt_k<<<129, 256, 0, stream>>>(W2, w_h0, b_h0, b_lin, Wf, cvec);
  fused_k<<<(N + 31) / 32, 256, 0, stream>>>(ego, edgeS, rowptr, h0, Wf, cvec,
                                             gamma, betaln, outf, N, E);
}

// Round 6
// 394.637 us; speedup vs baseline: 1.8307x; 1.0834x over previous
//
#include <hip/hip_runtime.h>

#define DD 128

// ---------- histogram of row indices ----------
__global__ void hist_k(const int* __restrict__ rowi, int* __restrict__ cnt, int E) {
  int e = blockIdx.x * 256 + threadIdx.x;
  if (e < E) atomicAdd(&cnt[rowi[e]], 1);
}

// ---------- scan stage 1: per-block (1024 elems) sums ----------
__global__ __launch_bounds__(256) void scan1_k(const int* __restrict__ cnt,
                                               int* __restrict__ bsum, int n) {
  __shared__ int red[256];
  int base = blockIdx.x * 1024 + threadIdx.x * 4;
  int s = 0;
  if (base + 3 < n) {
    int4 v = *(const int4*)(cnt + base);
    s = v.x + v.y + v.z + v.w;
  } else {
#pragma unroll
    for (int j = 0; j < 4; ++j) if (base + j < n) s += cnt[base + j];
  }
  red[threadIdx.x] = s;
  __syncthreads();
#pragma unroll
  for (int off = 128; off > 0; off >>= 1) {
    if (threadIdx.x < off) red[threadIdx.x] += red[threadIdx.x + off];
    __syncthreads();
  }
  if (threadIdx.x == 0) bsum[blockIdx.x] = red[0];
}

// ---------- scan stage 2: exclusive scan of block sums (nb <= 256) ----------
__global__ __launch_bounds__(256) void scan2_k(int* __restrict__ bsum, int nb) {
  __shared__ int part[256];
  int t = threadIdx.x;
  int v = (t < nb) ? bsum[t] : 0;
  part[t] = v;
  __syncthreads();
#pragma unroll
  for (int off = 1; off < 256; off <<= 1) {
    int u = (t >= off) ? part[t - off] : 0;
    __syncthreads();
    part[t] += u;
    __syncthreads();
  }
  if (t < nb) bsum[t] = part[t] - v;  // exclusive prefix
}

// ---------- scan stage 3: local scan + global offset -> rowptr, cursor ----------
__global__ __launch_bounds__(256) void scan3_k(const int* __restrict__ cnt,
                                               const int* __restrict__ bsum,
                                               int* __restrict__ rowptr,
                                               int* __restrict__ cursor, int n, int E) {
  __shared__ int tsum[256];
  int base = blockIdx.x * 1024 + threadIdx.x * 4;
  int v0 = 0, v1 = 0, v2 = 0, v3 = 0;
  if (base + 3 < n) {
    int4 v = *(const int4*)(cnt + base);
    v0 = v.x; v1 = v.y; v2 = v.z; v3 = v.w;
  } else {
    if (base + 0 < n) v0 = cnt[base + 0];
    if (base + 1 < n) v1 = cnt[base + 1];
    if (base + 2 < n) v2 = cnt[base + 2];
    if (base + 3 < n) v3 = cnt[base + 3];
  }
  int s = v0 + v1 + v2 + v3;
  tsum[threadIdx.x] = s;
  __syncthreads();
#pragma unroll
  for (int off = 1; off < 256; off <<= 1) {
    int u = (threadIdx.x >= off) ? tsum[threadIdx.x - off] : 0;
    __syncthreads();
    tsum[threadIdx.x] += u;
    __syncthreads();
  }
  int run = bsum[blockIdx.x] + tsum[threadIdx.x] - s;  // exclusive for this thread
  int p1 = run + v0, p2 = p1 + v1, p3 = p2 + v2;
  if (base + 3 < n) {
    *(int4*)(rowptr + base) = (int4){run, p1, p2, p3};
    *(int4*)(cursor + base) = (int4){run, p1, p2, p3};
  } else {
    if (base + 0 < n) { rowptr[base + 0] = run; cursor[base + 0] = run; }
    if (base + 1 < n) { rowptr[base + 1] = p1;  cursor[base + 1] = p1; }
    if (base + 2 < n) { rowptr[base + 2] = p2;  cursor[base + 2] = p2; }
    if (base + 3 < n) { rowptr[base + 3] = p3;  cursor[base + 3] = p3; }
  }
  if (blockIdx.x == 0 && threadIdx.x == 0) rowptr[n] = E;
}

// ---------- scatter edges into CSR order (packed int2: col, val-bits) ----------
__global__ void scatter_k(const int* __restrict__ rowi, const int* __restrict__ coli,
                          const float* __restrict__ vals, int* __restrict__ cursor,
                          int2* __restrict__ edgeS, int E) {
  int e = blockIdx.x * 256 + threadIdx.x;
  if (e < E) {
    int r = rowi[e];
    int p = atomicAdd(&cursor[r], 1);
    edgeS[p] = make_int2(coli[e], __float_as_int(vals[e]));
  }
}

// ---------- W2 = IM @ w_lin^T  (IM = (1-beta) + beta*weight) ----------
__global__ void w2_k(const float* __restrict__ weight, const float* __restrict__ w_lin,
                     float* __restrict__ W2) {
  const float BETA = 0.40546510810816438f;  // log(1.5)
  int idx = blockIdx.x * 256 + threadIdx.x; // 0..16383 exact
  int i = idx >> 7, j = idx & 127;
  const float* wi = weight + i * DD;
  const float* lj = w_lin + j * DD;
  float s = 0.f;
#pragma unroll 8
  for (int k = 0; k < DD; ++k) s = fmaf(fmaf(BETA, wi[k], 1.0f - BETA), lj[k], s);
  W2[idx] = s;  // W2[i][j]
}

// ---------- Wf (f32, [k=256][n=128]): rows 0..127 = 0.9*W2, rows 128..255 = 0.1*w_h0^T@W2 ----------
__global__ void wt_k(const float* __restrict__ W2, const float* __restrict__ w_h0,
                     const float* __restrict__ b_h0, const float* __restrict__ b_lin,
                     float* __restrict__ Wf, float* __restrict__ cvec) {
  int idx = blockIdx.x * 256 + threadIdx.x;
  if (idx < 16384) {
    Wf[idx] = 0.9f * W2[idx];                       // Wf[k][n] = 0.9*W2[k][n]
  } else if (idx < 32768) {
    int t = idx - 16384;
    int p = t >> 7, n = t & 127;
    float s = 0.f;
#pragma unroll 8
    for (int k = 0; k < DD; ++k) s = fmaf(w_h0[k * DD + p], W2[k * DD + n], s);
    Wf[(128 + p) * DD + n] = 0.1f * s;              // B[p][n] = sum_k w_h0[k][p]*W2[k][n]
  } else if (idx < 32896) {
    int n = idx - 32768;
    float s = 0.f;
    for (int k = 0; k < DD; ++k) s = fmaf(b_h0[k], W2[k * DD + n], s);
    cvec[n] = fmaf(0.1f, s, b_lin[n]);
  }
}

// ---------- fused: gather SpMM -> f32 GEMM -> bias+LeakyReLU+LayerNorm ----------
// Block = 256 threads = 4 waves; each wave owns 4 rows (block = 16 rows).
// Gather: per row, all 64 lanes cooperatively load up to 64 edges' meta (ONE
// coalesced load), then the pair loop gets (col,val) via __shfl broadcast —
// no metadata latency in the gather chain. Lanes 0-31 gather even edges,
// 32-63 odd edges; each lane loads float4 (one instr = 2 rows of ego).
// Out-of-range meta lanes are padded (col=0,v=0) -> branch-free inner loop.
// LDS = 16 KiB/block (4 KiB/wave) -> occupancy capped by HW 32 waves/CU.
__global__ __launch_bounds__(256) void fused_k(
    const float* __restrict__ ego, const int2* __restrict__ edgeS,
    const int* __restrict__ rowptr, const float* __restrict__ h0,
    const float* __restrict__ Wf, const float* __restrict__ cvec,
    const float* __restrict__ gamma, const float* __restrict__ betaln,
    float* __restrict__ out, int n) {
  __shared__ float lds[4][1024];  // 16 KiB total: per-wave 4 rows x 256 cols
  int wave = threadIdx.x >> 6;
  int lane = threadIdx.x & 63;
  int half = lane >> 5;   // 0 = even edges / S-writer, 1 = odd edges / h0-writer
  int q = lane & 31;      // float4 slot within a row
  float* xs = &lds[wave][0];
  int row0 = blockIdx.x * 16 + wave * 4;
  const float4* eg4 = (const float4*)ego;
  const float4* h4 = (const float4*)h0;

  // ---- phase 1: gather 4 rows into LDS ----
#pragma unroll
  for (int t = 0; t < 4; ++t) {
    int r = row0 + t;
    if (r >= n) r = n - 1;
    float4 acc = (half == 0) ? eg4[(size_t)r * 32 + q] : (float4){0.f, 0.f, 0.f, 0.f};
    float4 acc2 = {0.f, 0.f, 0.f, 0.f};
    float4 hrow = h4[(size_t)r * 32 + q];  // both halves hit same lines (free)
    int beg = rowptr[r], end = rowptr[r + 1];
    for (int cb = beg; cb < end; cb += 64) {
      int cnt = end - cb;
      if (cnt > 64) cnt = 64;
      // cooperative metadata load: one coalesced int2 load covers <=64 edges
      int mcol = 0;
      float mval = 0.f;
      if (lane < cnt) {
        int2 m = edgeS[cb + lane];
        mcol = m.x;
        mval = __int_as_float(m.y);
      }
      int npair = (cnt + 1) >> 1;  // max idx touched = 2*npair-1 <= cnt (padded safe)
      int j = 0;
      for (; j + 4 <= npair; j += 4) {
        int i0 = 2 * j + half;
        int c0 = __shfl(mcol, i0, 64);
        int c1 = __shfl(mcol, i0 + 2, 64);
        int c2 = __shfl(mcol, i0 + 4, 64);
        int c3 = __shfl(mcol, i0 + 6, 64);
        float v0 = __shfl(mval, i0, 64);
        float v1 = __shfl(mval, i0 + 2, 64);
        float v2 = __shfl(mval, i0 + 4, 64);
        float v3 = __shfl(mval, i0 + 6, 64);
        float4 g0 = eg4[(size_t)c0 * 32 + q];
        float4 g1 = eg4[(size_t)c1 * 32 + q];
        float4 g2 = eg4[(size_t)c2 * 32 + q];
        float4 g3 = eg4[(size_t)c3 * 32 + q];
        acc.x  = fmaf(v0, g0.x, acc.x);  acc.y  = fmaf(v0, g0.y, acc.y);
        acc.z  = fmaf(v0, g0.z, acc.z);  acc.w  = fmaf(v0, g0.w, acc.w);
        acc2.x = fmaf(v1, g1.x, acc2.x); acc2.y = fmaf(v1, g1.y, acc2.y);
        acc2.z = fmaf(v1, g1.z, acc2.z); acc2.w = fmaf(v1, g1.w, acc2.w);
        acc.x  = fmaf(v2, g2.x, acc.x);  acc.y  = fmaf(v2, g2.y, acc.y);
        acc.z  = fmaf(v2, g2.z, acc.z);  acc.w  = fmaf(v2, g2.w, acc.w);
        acc2.x = fmaf(v3, g3.x, acc2.x); acc2.y = fmaf(v3, g3.y, acc2.y);
        acc2.z = fmaf(v3, g3.z, acc2.z); acc2.w = fmaf(v3, g3.w, acc2.w);
      }
      for (; j < npair; ++j) {
        int i0 = 2 * j + half;
        int c0 = __shfl(mcol, i0, 64);
        float v0 = __shfl(mval, i0, 64);
        float4 g0 = eg4[(size_t)c0 * 32 + q];
        acc.x = fmaf(v0, g0.x, acc.x); acc.y = fmaf(v0, g0.y, acc.y);
        acc.z = fmaf(v0, g0.z, acc.z); acc.w = fmaf(v0, g0.w, acc.w);
      }
    }
    acc.x += acc2.x; acc.y += acc2.y; acc.z += acc2.z; acc.w += acc2.w;
    // fold halves (lane pair q / q+32 holds partials of cols 4q..4q+3)
    acc.x += __shfl_xor(acc.x, 32, 64);
    acc.y += __shfl_xor(acc.y, 32, 64);
    acc.z += __shfl_xor(acc.z, 32, 64);
    acc.w += __shfl_xor(acc.w, 32, 64);
    if (half == 0) *(float4*)(xs + t * 256 + 4 * q) = acc;        // S part
    else           *(float4*)(xs + t * 256 + 128 + 4 * q) = hrow; // h0 part
  }

  // ---- phase 2: GEMM, 4 rows x 2 cols per lane, k = 0..255 step 4 ----
  float acc0[4], acc1[4];
#pragma unroll
  for (int r = 0; r < 4; ++r) { acc0[r] = 0.f; acc1[r] = 0.f; }

  for (int kb = 0; kb < 64; ++kb) {
    int k = kb * 4;
    float wA0 = Wf[(k + 0) * DD + lane];
    float wA1 = Wf[(k + 1) * DD + lane];
    float wA2 = Wf[(k + 2) * DD + lane];
    float wA3 = Wf[(k + 3) * DD + lane];
    float wB0 = Wf[(k + 0) * DD + 64 + lane];
    float wB1 = Wf[(k + 1) * DD + 64 + lane];
    float wB2 = Wf[(k + 2) * DD + 64 + lane];
    float wB3 = Wf[(k + 3) * DD + 64 + lane];
#pragma unroll
    for (int r = 0; r < 4; ++r) {
      float4 xv = *(const float4*)(xs + r * 256 + k);  // broadcast, conflict-free
      acc0[r] = fmaf(xv.x, wA0, acc0[r]);
      acc0[r] = fmaf(xv.y, wA1, acc0[r]);
      acc0[r] = fmaf(xv.z, wA2, acc0[r]);
      acc0[r] = fmaf(xv.w, wA3, acc0[r]);
      acc1[r] = fmaf(xv.x, wB0, acc1[r]);
      acc1[r] = fmaf(xv.y, wB1, acc1[r]);
      acc1[r] = fmaf(xv.z, wB2, acc1[r]);
      acc1[r] = fmaf(xv.w, wB3, acc1[r]);
    }
  }

  // ---- epilogue: bias + leaky, stash rows (stride 132) in own LDS region ----
  float cb0 = cvec[lane], cb1 = cvec[64 + lane];
#pragma unroll
  for (int r = 0; r < 4; ++r) {
    float t0 = acc0[r] + cb0;
    t0 = (t0 > 0.f) ? t0 : 0.01f * t0;
    float t1 = acc1[r] + cb1;
    t1 = (t1 > 0.f) ? t1 : 0.01f * t1;
    xs[r * 132 + lane] = t0;
    xs[r * 132 + 64 + lane] = t1;
  }
  // same wave reads its own region; in-order DS ops make this safe without a barrier

  // ---- LN: lane -> (row = lane>>4, 8-col chunk p = lane&15) ----
  int r = lane >> 4, p = lane & 15;
  const float* base = xs + r * 132 + p * 8;  // 16B-aligned: 132*4*r %16==0, 32*p %16==0
  float4 va[2];
  float s = 0.f, qq = 0.f;
#pragma unroll
  for (int j = 0; j < 2; ++j) {
    float4 t = *(const float4*)(base + j * 4);
    va[j] = t;
    s += t.x + t.y + t.z + t.w;
    qq = fmaf(t.x, t.x, qq);
    qq = fmaf(t.y, t.y, qq);
    qq = fmaf(t.z, t.z, qq);
    qq = fmaf(t.w, t.w, qq);
  }
  s += __shfl_xor(s, 1, 64);
  s += __shfl_xor(s, 2, 64);
  s += __shfl_xor(s, 4, 64);
  s += __shfl_xor(s, 8, 64);
  qq += __shfl_xor(qq, 1, 64);
  qq += __shfl_xor(qq, 2, 64);
  qq += __shfl_xor(qq, 4, 64);
  qq += __shfl_xor(qq, 8, 64);
  float mean = s * (1.f / 128.f);
  float var = fmaf(qq, 1.f / 128.f, -mean * mean);
  float rstd = rsqrtf(var + 1e-5f);

  int orow = row0 + r;
  if (orow < n) {
    float* op = out + (size_t)orow * DD + p * 8;
    const float* gp = gamma + p * 8;
    const float* bp = betaln + p * 8;
#pragma unroll
    for (int j = 0; j < 2; ++j) {
      float4 g = *(const float4*)(gp + j * 4);
      float4 b = *(const float4*)(bp + j * 4);
      float4 o;
      o.x = fmaf((va[j].x - mean) * rstd, g.x, b.x);
      o.y = fmaf((va[j].y - mean) * rstd, g.y, b.y);
      o.z = fmaf((va[j].z - mean) * rstd, g.z, b.z);
      o.w = fmaf((va[j].w - mean) * rstd, g.w, b.w);
      *(float4*)(op + j * 4) = o;
    }
  }
}

extern "C" void kernel_launch(void* const* d_in, const int* in_sizes, int n_in,
                              void* d_out, int out_size, void* d_ws, size_t ws_size,
                              hipStream_t stream) {
  const float* ego    = (const float*)d_in[0];
  const float* h0     = (const float*)d_in[1];
  const float* vals   = (const float*)d_in[2];
  const int*   rowi   = (const int*)d_in[3];
  const int*   coli   = (const int*)d_in[4];
  const float* weight = (const float*)d_in[5];
  const float* w_h0   = (const float*)d_in[6];
  const float* b_h0   = (const float*)d_in[7];
  const float* w_lin  = (const float*)d_in[8];
  const float* b_lin  = (const float*)d_in[9];
  const float* gamma  = (const float*)d_in[10];
  const float* betaln = (const float*)d_in[11];

  const int N = in_sizes[0] / DD;
  const int E = in_sizes[2];
  const int NB = (N + 1023) / 1024;  // scan blocks (98 for N=100000, <=256 required)

  char* p = (char*)d_ws;
  auto carve = [&](size_t bytes) {
    char* q = p;
    p += (bytes + 255) & ~(size_t)255;
    return q;
  };
  int*   cnt    = (int*)carve((size_t)N * 4);
  int*   rowptr = (int*)carve((size_t)(N + 1) * 4);
  int*   cursor = (int*)carve((size_t)(N + 1) * 4);
  int*   bsum   = (int*)carve((size_t)256 * 4);
  int2*  edgeS  = (int2*)carve((size_t)E * 8);
  float* W2     = (float*)carve(16384 * 4);
  float* Wf     = (float*)carve(32768 * 4);
  float* cvec   = (float*)carve(128 * 4);
  (void)n_in; (void)out_size; (void)ws_size;

  float* outf = (float*)d_out;

  hipMemsetAsync(cnt, 0, (size_t)N * 4, stream);
  hist_k<<<(E + 255) / 256, 256, 0, stream>>>(rowi, cnt, E);
  w2_k<<<64, 256, 0, stream>>>(weight, w_lin, W2);
  scan1_k<<<NB, 256, 0, stream>>>(cnt, bsum, N);
  scan2_k<<<1, 256, 0, stream>>>(bsum, NB);
  scan3_k<<<NB, 256, 0, stream>>>(cnt, bsum, rowptr, cursor, N, E);
  scatter_k<<<(E + 255) / 256, 256, 0, stream>>>(rowi, coli, vals, cursor, edgeS, E);
  wt_k<<<129, 256, 0, stream>>>(W2, w_h0, b_h0, b_lin, Wf, cvec);
  fused_k<<<(N + 15) / 16, 256, 0, stream>>>(ego, edgeS, rowptr, h0, Wf, cvec,
                                             gamma, betaln, outf, N);
}